// Round 4
// baseline (1902.251 us; speedup 1.0000x reference)
//
#include <hip/hip_runtime.h>
#include <hip/hip_bf16.h>
#include <stdint.h>

#define S_LEN  2048
#define BATCH  16
#define HDIM   512
#define HIDIM  1024
#define NLAYER 3
#define SCAN_C 32
#define SCAN_T 64

typedef __hip_bfloat16 bf16;
typedef __attribute__((ext_vector_type(8))) short bf16x8;
typedef __attribute__((ext_vector_type(4))) float f32x4;
typedef unsigned int u32;

// ---------------------------------------------------------------- dtype probe
// flag=1: float buffers are f32; flag=0: bf16.
// f32 data read as u16: low-half words have random exponents -> many |bf16|>4.
__global__ void probe_dtype(const unsigned short* __restrict__ w, int* __restrict__ flag)
{
  int cnt = 0;
  for (int i = threadIdx.x; i < 4096; i += 64) {
    unsigned short m = w[i] & 0x7FFF;
    if (m > 0x4080) cnt++;              // |x| > 4.0 (or inf/nan), integer compare
  }
  for (int o = 32; o; o >>= 1) cnt += __shfl_down(cnt, o, 64);
  if (threadIdx.x == 0) *flag = (cnt > 64) ? 1 : 0;
}

// ---------------------------------------------------------------- activation
// a = sigmoid(-gate) = 1-z ; v = sigmoid(gate) * g(hidden). Overflow-safe.
__device__ __forceinline__ void av_calc(float hid, float gate, float& a, float& v) {
  a = 1.0f / (1.0f + __expf(gate));
  float z = 1.0f / (1.0f + __expf(-gate));
  float g = (hid >= 0.0f) ? (hid + 0.5f) : (1.0f / (1.0f + __expf(-hid)));
  v = z * g;
}

__device__ __forceinline__ short f2bs(float f) {
  bf16 h = (bf16)f;
  return *(short*)&h;
}

__device__ __forceinline__ bf16x8 pack8(float4 a, float4 b) {
  bf16x8 r;
  r[0] = f2bs(a.x); r[1] = f2bs(a.y); r[2] = f2bs(a.z); r[3] = f2bs(a.w);
  r[4] = f2bs(b.x); r[5] = f2bs(b.y); r[6] = f2bs(b.z); r[7] = f2bs(b.w);
  return r;
}

// ---------------------------------------------------------------- GEMM
// C[M,N] = A[M,K] * Bt[N,K]^T ; Bt bf16 row stride K; C bf16 row stride ldc.
// GATHER: A row = gidx[m], A dtype per *flag (f32 or bf16), row stride lda.
// !GATHER: A bf16, row stride lda. M,N mult of 128; K mult of 32.
template<int GATHER, int BIAS>
__global__ __launch_bounds__(256, 2)
void gemm_mfma(const void* __restrict__ Av, const bf16* __restrict__ Bt,
               bf16* __restrict__ Cout, const float* __restrict__ bias,
               const int* __restrict__ gidx, const int* __restrict__ flag,
               int M, int N, int K, int lda, int ldc)
{
  __shared__ bf16 As[128 * 32];
  __shared__ bf16 Bs[128 * 32];

  const int tid  = threadIdx.x;
  const int wave = tid >> 6;
  const int lane = tid & 63;
  const int m0 = blockIdx.y * 128;
  const int n0 = blockIdx.x * 128;

  const int seg0 = wave * 2, seg1 = seg0 + 1;
  const int lr = lane >> 2;          // row within 16-row segment
  const int ck = (lane & 3) * 8;     // k-chunk start (elements)
  const int rA0 = seg0 * 16 + lr;
  const int rA1 = seg1 * 16 + lr;

  const int af = GATHER ? *flag : 0;   // uniform

  long ga0 = GATHER ? (long)gidx[m0 + rA0] : (long)(m0 + rA0);
  long ga1 = GATHER ? (long)gidx[m0 + rA1] : (long)(m0 + rA1);
  const bf16*  hA0 = (const bf16*)Av + ga0 * (long)lda + ck;
  const bf16*  hA1 = (const bf16*)Av + ga1 * (long)lda + ck;
  const float* qA0 = (const float*)Av + ga0 * (long)lda + ck;
  const float* qA1 = (const float*)Av + ga1 * (long)lda + ck;
  const bf16*  pB0 = Bt + (long)(n0 + rA0) * K + ck;
  const bf16*  pB1 = Bt + (long)(n0 + rA1) * K + ck;

  bf16* lA0 = &As[seg0 * 512 + lane * 8];
  bf16* lA1 = &As[seg1 * 512 + lane * 8];
  bf16* lB0 = &Bs[seg0 * 512 + lane * 8];
  bf16* lB1 = &Bs[seg1 * 512 + lane * 8];

  f32x4 acc[4][4];
#pragma unroll
  for (int i = 0; i < 4; i++)
#pragma unroll
    for (int j = 0; j < 4; j++)
#pragma unroll
      for (int r = 0; r < 4; r++) acc[i][j][r] = 0.0f;

  const int mBase = (wave >> 1) * 64;
  const int nBase = (wave & 1) * 64;
  const int fr = lane & 15;
  const int fq = (lane >> 4) * 8;

  for (int k0 = 0; k0 < K; k0 += 32) {
    bf16x8 va0, va1;
    if (GATHER && af) {
      float4 a0 = *(const float4*)(qA0 + k0);
      float4 a1 = *(const float4*)(qA0 + k0 + 4);
      float4 b0 = *(const float4*)(qA1 + k0);
      float4 b1 = *(const float4*)(qA1 + k0 + 4);
      va0 = pack8(a0, a1);
      va1 = pack8(b0, b1);
    } else {
      va0 = *(const bf16x8*)(hA0 + k0);
      va1 = *(const bf16x8*)(hA1 + k0);
    }
    bf16x8 vb0 = *(const bf16x8*)(pB0 + k0);
    bf16x8 vb1 = *(const bf16x8*)(pB1 + k0);
    __syncthreads();   // previous iteration's fragment reads complete
    *(bf16x8*)lA0 = va0;
    *(bf16x8*)lA1 = va1;
    *(bf16x8*)lB0 = vb0;
    *(bf16x8*)lB1 = vb1;
    __syncthreads();   // staging visible

    bf16x8 afr[4], bfr[4];
#pragma unroll
    for (int mt = 0; mt < 4; mt++)
      afr[mt] = *(const bf16x8*)&As[(mBase + mt * 16 + fr) * 32 + fq];
#pragma unroll
    for (int nt = 0; nt < 4; nt++)
      bfr[nt] = *(const bf16x8*)&Bs[(nBase + nt * 16 + fr) * 32 + fq];

#pragma unroll
    for (int mt = 0; mt < 4; mt++)
#pragma unroll
      for (int nt = 0; nt < 4; nt++)
        acc[mt][nt] = __builtin_amdgcn_mfma_f32_16x16x32_bf16(afr[mt], bfr[nt], acc[mt][nt], 0, 0, 0);
  }

  // C/D layout: col = lane&15, row = (lane>>4)*4 + reg
  const int orow = (lane >> 4) * 4;
  const int ocol = lane & 15;
#pragma unroll
  for (int mt = 0; mt < 4; mt++) {
#pragma unroll
    for (int nt = 0; nt < 4; nt++) {
      int gr = m0 + mBase + mt * 16 + orow;
      int gc = n0 + nBase + nt * 16 + ocol;
      float bv = BIAS ? bias[gc] : 0.0f;
#pragma unroll
      for (int r = 0; r < 4; r++) {
        float v = acc[mt][nt][r] + bv;
        Cout[(long)(gr + r) * ldc + gc] = (bf16)v;
      }
    }
  }
}

// ---------------------------------------------------------------- converters
// transpose+convert: in [R,C] (f32 or bf16 per flag) -> bf16 [C,R]
__global__ __launch_bounds__(256)
void transpose_conv(const void* __restrict__ in, bf16* __restrict__ out,
                    const int* __restrict__ flag, int R, int C)
{
  __shared__ float tile[32][33];
  int f = *flag;
  int x = blockIdx.x * 32 + threadIdx.x;
  int yb = blockIdx.y * 32;
#pragma unroll
  for (int i = threadIdx.y; i < 32; i += 8) {
    long idx = (long)(yb + i) * C + x;
    tile[i][threadIdx.x] = f ? ((const float*)in)[idx] : (float)((const bf16*)in)[idx];
  }
  __syncthreads();
  int x2 = yb + threadIdx.x;
  int y2b = blockIdx.x * 32;
#pragma unroll
  for (int i = threadIdx.y; i < 32; i += 8)
    out[(long)(y2b + i) * R + x2] = (bf16)tile[threadIdx.x][i];
}

__global__ __launch_bounds__(256)
void conv_to_f32(const void* __restrict__ in, float* __restrict__ out,
                 const int* __restrict__ flag, int n)
{
  int i = blockIdx.x * blockDim.x + threadIdx.x;
  if (i >= n) return;
  out[i] = (*flag) ? ((const float*)in)[i] : (float)((const bf16*)in)[i];
}

// ---------------------------------------------------------------- scan
// HG: bf16 [bch*S_LEN, 2048]; cols 0..1023 hidden, 1024..2047 gate.
// Chain=(b,c); chunk j of SCAN_T. tid = ((b*SCAN_C+j)<<10)|c.
__global__ __launch_bounds__(256)
void scan_pass1(const bf16* __restrict__ HG, float* __restrict__ Ab, float* __restrict__ Pb)
{
  int tid = blockIdx.x * blockDim.x + threadIdx.x;
  int c  = tid & (HIDIM - 1);
  int bj = tid >> 10;
  int j  = bj & (SCAN_C - 1);
  int b  = bj >> 5;
  const bf16* base = HG + ((long)(b * S_LEN + j * SCAN_T)) * 2048 + c;
  float A = 1.0f, P = 0.0f;
#pragma unroll 4
  for (int t = 0; t < SCAN_T; t++) {
    float hid = (float)base[(long)t * 2048];
    float gt  = (float)base[(long)t * 2048 + 1024];
    float a, v; av_calc(hid, gt, a, v);
    A *= a;
    P = fmaf(a, P, v);
  }
  Ab[tid] = A;
  Pb[tid] = P;
}

__global__ __launch_bounds__(256)
void scan_pass2(const float* __restrict__ Ab, float* __restrict__ Pb)
{
  int tid = blockIdx.x * blockDim.x + threadIdx.x;
  int c = tid & (HIDIM - 1);
  int b = tid >> 10;
  float h = 0.0f;
  for (int j = 0; j < SCAN_C; j++) {
    long i = ((long)(b * SCAN_C + j) << 10) + c;
    float A = Ab[i];
    float P = Pb[i];
    Pb[i] = h;
    h = fmaf(A, h, P);
  }
}

__global__ __launch_bounds__(256)
void scan_pass3(bf16* __restrict__ HG, const float* __restrict__ Pb)
{
  int tid = blockIdx.x * blockDim.x + threadIdx.x;
  int c  = tid & (HIDIM - 1);
  int bj = tid >> 10;
  int j  = bj & (SCAN_C - 1);
  int b  = bj >> 5;
  bf16* base = HG + ((long)(b * S_LEN + j * SCAN_T)) * 2048 + c;
  float h = Pb[tid];
#pragma unroll 4
  for (int t = 0; t < SCAN_T; t++) {
    float hid = (float)base[(long)t * 2048];
    float gt  = (float)base[(long)t * 2048 + 1024];
    float a, v; av_calc(hid, gt, a, v);
    h = fmaf(a, h, v);
    base[(long)t * 2048] = (bf16)h;   // h lives in hidden cols
  }
}

// ---------------------------------------------------------------- shift / output
// rev[b,t] = x[b, S-1-((t+pad) mod S)], pad = S - len; transform is an involution.
__global__ __launch_bounds__(256)
void rev_build(const bf16* __restrict__ X, bf16* __restrict__ X2, const int* __restrict__ lens)
{
  int bt = blockIdx.x;
  int b = bt >> 11;
  int t = bt & (S_LEN - 1);
  int pad = S_LEN - lens[b];
  int src = S_LEN - 1 - ((t + pad) & (S_LEN - 1));
  const u32* s = (const u32*)(X + (long)(b * S_LEN + src) * HDIM);
  u32* d = (u32*)(X2 + (long)(b * S_LEN + t) * HDIM);
  d[threadIdx.x] = s[threadIdx.x];
}

// out[b,t] = concat(X[b,t], X2[b,src(t)]); dtype per flag
__global__ __launch_bounds__(256)
void finalize_out(const bf16* __restrict__ X, const bf16* __restrict__ X2,
                  const int* __restrict__ lens, const int* __restrict__ flag,
                  void* __restrict__ out)
{
  int bt = blockIdx.x;
  int b = bt >> 11;
  int t = bt & (S_LEN - 1);
  int pad = S_LEN - lens[b];
  int src = S_LEN - 1 - ((t + pad) & (S_LEN - 1));
  const bf16* sf = X  + (long)(b * S_LEN + t) * HDIM;
  const bf16* sr = X2 + (long)(b * S_LEN + src) * HDIM;
  long ro = (long)(b * S_LEN + t) * 1024;
  if (*flag) {
    float* d = (float*)out + ro;
    for (int c = threadIdx.x; c < 512; c += 256) {
      d[c]       = (float)sf[c];
      d[512 + c] = (float)sr[c];
    }
  } else {
    bf16* d = (bf16*)out + ro;
    for (int c = threadIdx.x; c < 512; c += 256) {
      d[c]       = sf[c];
      d[512 + c] = sr[c];
    }
  }
}

// seq_h[b] = concat(X[b,len-1], X2[b,0])  (src(len-1)==0)
__global__ __launch_bounds__(256)
void seq_out_k(const bf16* __restrict__ X, const bf16* __restrict__ X2,
               const int* __restrict__ lens, const int* __restrict__ flag,
               void* __restrict__ out)
{
  int b = blockIdx.x;
  int t = lens[b] - 1;
  const bf16* sf = X  + (long)(b * S_LEN + t) * HDIM;
  const bf16* sr = X2 + (long)(b * S_LEN + 0) * HDIM;
  long off = (long)BATCH * S_LEN * 1024 + (long)b * 1024;
  if (*flag) {
    float* d = (float*)out + off;
    for (int c = threadIdx.x; c < 512; c += 256) {
      d[c]       = (float)sf[c];
      d[512 + c] = (float)sr[c];
    }
  } else {
    bf16* d = (bf16*)out + off;
    for (int c = threadIdx.x; c < 512; c += 256) {
      d[c]       = sf[c];
      d[512 + c] = sr[c];
    }
  }
}

// ---------------------------------------------------------------- launch
extern "C" void kernel_launch(void* const* d_in, const int* in_sizes, int n_in,
                              void* d_out, int out_size, void* d_ws, size_t ws_size,
                              hipStream_t stream)
{
  (void)in_sizes; (void)n_in; (void)out_size;
  const int* x_source = (const int*)d_in[0];
  const int* x_len    = (const int*)d_in[1];
  const void* emb     = d_in[2];
  const void* W_er    = d_in[3];
  const void* b_er    = d_in[4];
  const void* W_hg[2]  = { d_in[5], d_in[7] };   // [3,512,2048]
  const void* W_out[2] = { d_in[6], d_in[8] };   // [3,1024,512]

  char* ws = (char*)d_ws;
  size_t off = 0;
  auto alloc = [&](size_t bytes) -> char* {
    char* p = ws + off;
    off += (bytes + 255) & ~(size_t)255;
    return p;
  };
  auto a256 = [](size_t b) -> size_t { return (b + 255) & ~(size_t)255; };

  int*   flag = (int*)  alloc(256);
  float* berF = (float*)alloc(512 * 4);
  bf16*  WerT = (bf16*) alloc((size_t)512 * 512 * 2);
  bf16*  X    = (bf16*) alloc((size_t)BATCH * S_LEN * HDIM * 2);   // fwd acts, 32 MB
  bf16*  X2   = (bf16*) alloc((size_t)BATCH * S_LEN * HDIM * 2);   // rev acts, 32 MB
  bf16* WhgT[2][NLAYER];
  bf16* WoutT[2][NLAYER];
  for (int d = 0; d < 2; d++)
    for (int l = 0; l < NLAYER; l++) {
      WhgT[d][l]  = (bf16*)alloc((size_t)2048 * 512 * 2);
      WoutT[d][l] = (bf16*)alloc((size_t)512 * 1024 * 2);
    }

  size_t fixedEnd = off;
  int bch = 16;
  while (bch > 1) {
    size_t need = fixedEnd
      + a256((size_t)bch * S_LEN * 2048 * 2)
      + 2 * a256((size_t)bch * SCAN_C * HIDIM * 4);
    if (need <= ws_size) break;
    bch >>= 1;
  }
  bf16*  HG = (bf16*) alloc((size_t)bch * S_LEN * 2048 * 2);
  float* Ab = (float*)alloc((size_t)bch * SCAN_C * HIDIM * 4);
  float* Pb = (float*)alloc((size_t)bch * SCAN_C * HIDIM * 4);

  probe_dtype<<<1, 64, 0, stream>>>((const unsigned short*)emb, flag);

  conv_to_f32<<<2, 256, 0, stream>>>(b_er, berF, flag, 512);
  dim3 tb(32, 8);
  transpose_conv<<<dim3(16, 16), tb, 0, stream>>>(W_er, WerT, flag, 512, 512);
  for (int d = 0; d < 2; d++)
    for (int l = 0; l < NLAYER; l++) {
      // byte offset depends on dtype -> pass element offset via max; use flag-agnostic trick:
      // we can't branch on dtype host-side, so offset in ELEMENTS is the same; bytes differ.
      // Solution: launch two transposes? No — compute both pointers, let kernel pick via flag.
      // Simpler: transpose_conv reads via flag; pass both candidate base pointers.
      // (handled below with a wrapper kernel signature change)
      (void)0;
    }
  // W_hg[d] layer l starts at element offset l*512*2048; as f32 that's *4 bytes, bf16 *2.
  // transpose_conv needs the layer base: give it the common element offset.
  for (int d = 0; d < 2; d++)
    for (int l = 0; l < NLAYER; l++) {
      const char* hg32 = (const char*)W_hg[d] + (size_t)l * 512 * 2048 * 4;
      const char* hg16 = (const char*)W_hg[d] + (size_t)l * 512 * 2048 * 2;
      const char* wo32 = (const char*)W_out[d] + (size_t)l * 1024 * 512 * 4;
      const char* wo16 = (const char*)W_out[d] + (size_t)l * 1024 * 512 * 2;
      // kernel picks base per flag: pass both via two launches is wrong; instead pass
      // the f32 base and bf16 base and select inside. Reuse transpose_conv with a
      // second pointer parameter packed as gridDim trick is ugly — use dedicated kernel:
      extern __global__ void transpose_conv2(const void*, const void*, bf16*, const int*, int, int);
      transpose_conv2<<<dim3(2048 / 32, 512 / 32), tb, 0, stream>>>(hg32, hg16, WhgT[d][l], flag, 512, 2048);
      transpose_conv2<<<dim3(512 / 32, 1024 / 32), tb, 0, stream>>>(wo32, wo16, WoutT[d][l], flag, 1024, 512);
    }

  // x_emb = emb[x_source] @ W_er + b_er -> X (bf16)
  gemm_mfma<1, 1><<<dim3(4, (BATCH * S_LEN) / 128), 256, 0, stream>>>(
      emb, WerT, X, berF, x_source, flag, BATCH * S_LEN, 512, 512, 512, 512);

  rev_build<<<BATCH * S_LEN, 256, 0, stream>>>(X, X2, x_len);

  for (int d = 0; d < 2; d++) {
    bf16* Xd = d ? X2 : X;
    for (int l = 0; l < NLAYER; l++) {
      for (int cb = 0; cb < BATCH / bch; cb++) {
        bf16* Ain = Xd + (size_t)cb * bch * S_LEN * HDIM;
        int Mrows = bch * S_LEN;
        gemm_mfma<0, 0><<<dim3(16, Mrows / 128), 256, 0, stream>>>(
            Ain, WhgT[d][l], HG, nullptr, nullptr, nullptr, Mrows, 2048, 512, 512, 2048);
        int nthr = bch * SCAN_C * HIDIM;
        scan_pass1<<<nthr / 256, 256, 0, stream>>>(HG, Ab, Pb);
        scan_pass2<<<(bch * HIDIM) / 256, 256, 0, stream>>>(Ab, Pb);
        scan_pass3<<<nthr / 256, 256, 0, stream>>>(HG, Pb);
        gemm_mfma<0, 0><<<dim3(4, Mrows / 128), 256, 0, stream>>>(
            HG, WoutT[d][l], Ain, nullptr, nullptr, nullptr, Mrows, 512, 1024, 2048, 512);
      }
    }
  }

  finalize_out<<<BATCH * S_LEN, 256, 0, stream>>>(X, X2, x_len, flag, d_out);
  seq_out_k<<<BATCH, 256, 0, stream>>>(X, X2, x_len, flag, d_out);
}

// dual-base transpose+convert: picks f32 or bf16 source per flag
__global__ __launch_bounds__(256)
void transpose_conv2(const void* __restrict__ in32, const void* __restrict__ in16,
                     bf16* __restrict__ out, const int* __restrict__ flag, int R, int C)
{
  __shared__ float tile[32][33];
  int f = *flag;
  int x = blockIdx.x * 32 + threadIdx.x;
  int yb = blockIdx.y * 32;
#pragma unroll
  for (int i = threadIdx.y; i < 32; i += 8) {
    long idx = (long)(yb + i) * C + x;
    tile[i][threadIdx.x] = f ? ((const float*)in32)[idx] : (float)((const bf16*)in16)[idx];
  }
  __syncthreads();
  int x2 = yb + threadIdx.x;
  int y2b = blockIdx.x * 32;
#pragma unroll
  for (int i = threadIdx.y; i < 32; i += 8)
    out[(long)(y2b + i) * R + x2] = (bf16)tile[threadIdx.x][i];
}